// Round 2
// baseline (717.654 us; speedup 1.0000x reference)
//
#include <hip/hip_runtime.h>
#include <hip/hip_bf16.h>
#include <math.h>

// ExpertPool: B=2,N=1024 -> T=2048 tokens, D=768, E=8, H=3072, top-K=2
#define T_TOK 2048
#define DIM   768
#define NEXP  8
#define HDIM  3072
#define MAXP  (T_TOK * 2)   // exactly 4096 (token,expert) pairs

typedef __attribute__((ext_vector_type(8))) short bfrag;   // 8 bf16 (4 VGPRs)
typedef __attribute__((ext_vector_type(4))) float f32x4;   // MFMA C/D

__device__ __forceinline__ unsigned short f2bf(float f) {
  union { float f; unsigned int u; } x; x.f = f;
  unsigned int r = x.u + 0x7fffu + ((x.u >> 16) & 1u);  // RNE
  return (unsigned short)(r >> 16);
}

// ---------------- routing: per-expert contiguous row lists ----------------
__global__ void k_route(const float* __restrict__ disp,
                        const float* __restrict__ comb,
                        int* __restrict__ meta,        // [0..7]=cnt, [8..15]=off
                        float* __restrict__ row_comb,
                        int* __restrict__ row_token) {
  __shared__ int s_cnt[NEXP], s_off[NEXP], s_cur[NEXP];
  int tid = threadIdx.x;
  if (tid < NEXP) s_cnt[tid] = 0;
  __syncthreads();
  for (int t = tid; t < T_TOK; t += blockDim.x)
    for (int e = 0; e < NEXP; ++e)
      if (disp[t * NEXP + e] > 0.f) atomicAdd(&s_cnt[e], 1);
  __syncthreads();
  if (tid == 0) {
    int acc = 0;
    for (int e = 0; e < NEXP; ++e) { s_off[e] = acc; acc += s_cnt[e]; }
  }
  __syncthreads();
  if (tid < NEXP) {
    s_cur[tid] = s_off[tid];
    meta[tid] = s_cnt[tid];
    meta[NEXP + tid] = s_off[tid];
  }
  __syncthreads();
  for (int t = tid; t < T_TOK; t += blockDim.x)
    for (int e = 0; e < NEXP; ++e)
      if (disp[t * NEXP + e] > 0.f) {
        int p = atomicAdd(&s_cur[e], 1);
        row_token[p] = t;
        row_comb[p] = comb[t * NEXP + e];
      }
}

// ------- GEMM 1 fused: u = gelu(X@Wg^T) * (X@Wv^T) -> bf16 (P,H) -------
// 128x128 tile, BK=32, one A staging + two B stagings, 32 MFMA per barrier.
// 1-D grid, XCD-aware: all M-tiles of a (e,n-tile) group share blk&7 -> same
// XCD L2 caches the two B slabs (heuristic, speed-only).
__global__ __launch_bounds__(256, 2) void k_gemm_gv(
    const float* __restrict__ X,        // (T_TOK, DIM)
    const float* __restrict__ Wg,       // (NEXP, HDIM, DIM)
    const float* __restrict__ Wv,       // (NEXP, HDIM, DIM)
    const int* __restrict__ meta,
    const int* __restrict__ row_token,
    unsigned short* __restrict__ ubuf)  // (MAXP, HDIM) bf16 raw
{
  int blk = blockIdx.x;                 // 8*24*16 = 3072
  int xcd = blk & 7;
  int rest = blk >> 3;
  int mt = rest & 15;                   // M-tile 0..15
  int gq = rest >> 4;                   // 0..23
  int group = gq * 8 + xcd;             // 0..191
  int e = group / 24;
  int nt = group % 24;

  int cnt = meta[e];
  int m0 = mt * 128;
  if (m0 >= cnt) return;
  int off = meta[NEXP + e];
  int n0 = nt * 128;

  __shared__ unsigned short As[128 * 32];
  __shared__ unsigned short Bgs[128 * 32];
  __shared__ unsigned short Bvs[128 * 32];

  int tid = threadIdx.x;
  int wid = tid >> 6, lane = tid & 63;
  int wm = (wid >> 1) * 64, wn = (wid & 1) * 64;
  int lr = lane & 15, quad = lane >> 4;

  int a_tok[4];
#pragma unroll
  for (int r = 0; r < 4; ++r) {
    int row = (tid + 256 * r) >> 3;
    int gr = m0 + row; if (gr >= cnt) gr = cnt - 1;
    a_tok[r] = row_token[off + gr];
  }

  const float* Wgb = Wg + (size_t)e * ((size_t)HDIM * DIM);
  const float* Wvb = Wv + (size_t)e * ((size_t)HDIM * DIM);

  f32x4 zero4 = {0.f, 0.f, 0.f, 0.f};
  f32x4 accg[4][4], accv[4][4];
#pragma unroll
  for (int i = 0; i < 4; ++i)
#pragma unroll
    for (int j = 0; j < 4; ++j) { accg[i][j] = zero4; accv[i][j] = zero4; }

  for (int k0 = 0; k0 < DIM; k0 += 32) {
    __syncthreads();
#pragma unroll
    for (int r = 0; r < 4; ++r) {
      int c = tid + 256 * r;
      int row = c >> 3, c4 = c & 7;
      float4 av = *(const float4*)(X + (size_t)a_tok[r] * DIM + k0 + c4 * 4);
      ushort4 ap;
      ap.x = f2bf(av.x); ap.y = f2bf(av.y); ap.z = f2bf(av.z); ap.w = f2bf(av.w);
      *(ushort4*)(&As[row * 32 + c4 * 4]) = ap;
      float4 gv = *(const float4*)(Wgb + (size_t)(n0 + row) * DIM + k0 + c4 * 4);
      ushort4 gp;
      gp.x = f2bf(gv.x); gp.y = f2bf(gv.y); gp.z = f2bf(gv.z); gp.w = f2bf(gv.w);
      *(ushort4*)(&Bgs[row * 32 + c4 * 4]) = gp;
      float4 vv = *(const float4*)(Wvb + (size_t)(n0 + row) * DIM + k0 + c4 * 4);
      ushort4 vp;
      vp.x = f2bf(vv.x); vp.y = f2bf(vv.y); vp.z = f2bf(vv.z); vp.w = f2bf(vv.w);
      *(ushort4*)(&Bvs[row * 32 + c4 * 4]) = vp;
    }
    __syncthreads();
    bfrag a[4], bg[4], bv[4];
#pragma unroll
    for (int i = 0; i < 4; ++i)
      a[i] = *(const bfrag*)(&As[(wm + i * 16 + lr) * 32 + quad * 8]);
#pragma unroll
    for (int j = 0; j < 4; ++j) {
      bg[j] = *(const bfrag*)(&Bgs[(wn + j * 16 + lr) * 32 + quad * 8]);
      bv[j] = *(const bfrag*)(&Bvs[(wn + j * 16 + lr) * 32 + quad * 8]);
    }
#pragma unroll
    for (int i = 0; i < 4; ++i)
#pragma unroll
      for (int j = 0; j < 4; ++j) {
        accg[i][j] = __builtin_amdgcn_mfma_f32_16x16x32_bf16(a[i], bg[j], accg[i][j], 0, 0, 0);
        accv[i][j] = __builtin_amdgcn_mfma_f32_16x16x32_bf16(a[i], bv[j], accv[i][j], 0, 0, 0);
      }
  }

  // epilogue: gelu_exact(g)*v on fp32 accumulators, then one bf16 round
#pragma unroll
  for (int i = 0; i < 4; ++i)
#pragma unroll
    for (int rg = 0; rg < 4; ++rg) {
      int gr = m0 + wm + i * 16 + quad * 4 + rg;
      if (gr < cnt) {
        size_t base = (size_t)(off + gr) * HDIM + n0 + wn;
#pragma unroll
        for (int j = 0; j < 4; ++j) {
          float g = accg[i][j][rg];
          float v = accv[i][j][rg];
          float u = 0.5f * g * (1.0f + erff(g * 0.70710678118654752f)) * v;
          ubuf[base + j * 16 + lr] = f2bf(u);
        }
      }
    }
}

// ------- GEMM 2: u @ Wo^T * scale*comb -> atomicAdd into out, split-K x4 -------
__global__ __launch_bounds__(256, 2) void k_gemm_out(
    const unsigned short* __restrict__ U,  // (MAXP, HDIM) bf16
    const float* __restrict__ Wo,          // (NEXP, DIM, HDIM)
    const float* __restrict__ scale,       // (NEXP)
    const int* __restrict__ meta,
    const int* __restrict__ row_token,
    const float* __restrict__ row_comb,
    float* __restrict__ out)               // (T_TOK, DIM), pre-zeroed
{
  int blk = blockIdx.x;                    // 8*24*16 = 3072
  int xcd = blk & 7;
  int rest = blk >> 3;
  int mt = rest & 15;                      // M-tile 0..15
  int gq = rest >> 4;                      // 0..23
  int group = gq * 8 + xcd;                // 0..191
  int e = group / 24;
  int r24 = group % 24;
  int nt = r24 / 4;                        // 0..5
  int ks = r24 % 4;                        // K-split 0..3

  int cnt = meta[e];
  int m0 = mt * 128;
  if (m0 >= cnt) return;
  int off = meta[NEXP + e];
  int n0 = nt * 128;
  int kbase = ks * (HDIM / 4);             // 768-wide K slice

  __shared__ unsigned short As[128 * 32];
  __shared__ unsigned short Bs[128 * 32];

  int tid = threadIdx.x;
  int wid = tid >> 6, lane = tid & 63;
  int wm = (wid >> 1) * 64, wn = (wid & 1) * 64;
  int lr = lane & 15, quad = lane >> 4;

  int a_grow[2];
#pragma unroll
  for (int r = 0; r < 2; ++r) {
    int row = (tid + 256 * r) >> 2;
    int gr = m0 + row; if (gr >= cnt) gr = cnt - 1;
    a_grow[r] = off + gr;
  }

  const float* Wb = Wo + (size_t)e * ((size_t)DIM * HDIM);

  f32x4 zero4 = {0.f, 0.f, 0.f, 0.f};
  f32x4 acc[4][4];
#pragma unroll
  for (int i = 0; i < 4; ++i)
#pragma unroll
    for (int j = 0; j < 4; ++j) acc[i][j] = zero4;

  for (int kk = 0; kk < HDIM / 4; kk += 32) {
    int k0 = kbase + kk;
    __syncthreads();
#pragma unroll
    for (int r = 0; r < 2; ++r) {
      int c = tid + 256 * r;
      int row = c >> 2, c8 = c & 3;
      uint4 av = *(const uint4*)(U + (size_t)a_grow[r] * HDIM + k0 + c8 * 8);
      *(uint4*)(&As[row * 32 + c8 * 8]) = av;
    }
#pragma unroll
    for (int r = 0; r < 4; ++r) {
      int c = tid + 256 * r;
      int row = c >> 3, c4 = c & 7;
      float4 bvv = *(const float4*)(Wb + (size_t)(n0 + row) * HDIM + k0 + c4 * 4);
      ushort4 bp;
      bp.x = f2bf(bvv.x); bp.y = f2bf(bvv.y); bp.z = f2bf(bvv.z); bp.w = f2bf(bvv.w);
      *(ushort4*)(&Bs[row * 32 + c4 * 4]) = bp;
    }
    __syncthreads();
    bfrag a[4], b[4];
#pragma unroll
    for (int i = 0; i < 4; ++i)
      a[i] = *(const bfrag*)(&As[(wm + i * 16 + lr) * 32 + quad * 8]);
#pragma unroll
    for (int j = 0; j < 4; ++j)
      b[j] = *(const bfrag*)(&Bs[(wn + j * 16 + lr) * 32 + quad * 8]);
#pragma unroll
    for (int i = 0; i < 4; ++i)
#pragma unroll
      for (int j = 0; j < 4; ++j)
        acc[i][j] = __builtin_amdgcn_mfma_f32_16x16x32_bf16(a[i], b[j], acc[i][j], 0, 0, 0);
  }

  float sc = scale[e];
#pragma unroll
  for (int i = 0; i < 4; ++i)
#pragma unroll
    for (int rg = 0; rg < 4; ++rg) {
      int gr = m0 + wm + i * 16 + quad * 4 + rg;
      if (gr < cnt) {
        int grow = off + gr;
        float w = row_comb[grow] * sc;
        int tok = row_token[grow];
        float* ob = out + (size_t)tok * DIM + n0 + wn;
#pragma unroll
        for (int j = 0; j < 4; ++j)
          atomicAdd(ob + j * 16 + lr, acc[i][j][rg] * w);
      }
    }
}

extern "C" void kernel_launch(void* const* d_in, const int* in_sizes, int n_in,
                              void* d_out, int out_size, void* d_ws, size_t ws_size,
                              hipStream_t stream) {
  const float* tokens = (const float*)d_in[0];
  const float* disp   = (const float*)d_in[1];
  const float* comb   = (const float*)d_in[2];
  const float* Wg     = (const float*)d_in[3];
  const float* Wv     = (const float*)d_in[4];
  const float* Wo     = (const float*)d_in[5];
  const float* scale  = (const float*)d_in[6];
  float* out = (float*)d_out;

  char* ws = (char*)d_ws;
  int*   meta      = (int*)ws;                       // 16 ints used
  int*   row_token = (int*)(ws + 1024);              // 4096 ints
  float* row_comb  = (float*)(ws + 1024 + 16384);    // 4096 floats
  unsigned short* ubuf = (unsigned short*)(ws + (1u << 20));  // 25 MB bf16

  hipMemsetAsync(d_out, 0, (size_t)out_size * sizeof(float), stream);
  hipLaunchKernelGGL(k_route, dim3(1), dim3(256), 0, stream,
                     disp, comb, meta, row_comb, row_token);
  // fused gate/value GEMM + gelu-mul epilogue: 8 xcd * 24 (e,nt) groups * 16 M-tiles
  hipLaunchKernelGGL(k_gemm_gv, dim3(8 * 24 * 16), dim3(256), 0, stream,
                     tokens, Wg, Wv, meta, row_token, ubuf);
  // output GEMM, split-K x4: 8 xcd * 24 (e,nt,ks) groups * 16 M-tiles
  hipLaunchKernelGGL(k_gemm_out, dim3(8 * 24 * 16), dim3(256), 0, stream,
                     ubuf, Wo, scale, meta, row_token, row_comb, out);
}

// Round 3
// 422.747 us; speedup vs baseline: 1.6976x; 1.6976x over previous
//
#include <hip/hip_runtime.h>
#include <hip/hip_bf16.h>
#include <math.h>

// ExpertPool: B=2,N=1024 -> T=2048 tokens, D=768, E=8, H=3072, top-K=2
#define T_TOK 2048
#define DIM   768
#define NEXP  8
#define HDIM  3072
#define MAXP  (T_TOK * 2)   // exactly 4096 (token,expert) pairs (softmax>0 => exactly top-2)
#define LDST  40            // LDS row stride in ushorts (80 B): breaks 8-way bank aliasing
#define NTILE_MAX 40        // sum ceil(cnt_e/128) <= 32+7 = 39

typedef __attribute__((ext_vector_type(8))) short bfrag;   // 8 bf16 (4 VGPRs)
typedef __attribute__((ext_vector_type(4))) float f32x4;   // MFMA C/D

__device__ __forceinline__ unsigned short f2bf(float f) {
  union { float f; unsigned int u; } x; x.f = f;
  unsigned int r = x.u + 0x7fffu + ((x.u >> 16) & 1u);  // RNE
  return (unsigned short)(r >> 16);
}

// ---------------- routing + tile table + token->pair map ----------------
__global__ void k_route(const float* __restrict__ disp,
                        const float* __restrict__ comb,
                        int* __restrict__ meta,        // [0..7]=cnt [8..15]=off [16]=ntiles [17..56]=tiles
                        float* __restrict__ row_comb,
                        int* __restrict__ row_token,
                        int* __restrict__ tok2pair) {  // (T_TOK,2)
  __shared__ int s_cnt[NEXP], s_off[NEXP], s_cur[NEXP];
  __shared__ int s_tn[T_TOK];
  int tid = threadIdx.x;
  if (tid < NEXP) s_cnt[tid] = 0;
  for (int t = tid; t < T_TOK; t += 256) s_tn[t] = 0;
  __syncthreads();
  for (int t = tid; t < T_TOK; t += 256)
    for (int e = 0; e < NEXP; ++e)
      if (disp[t * NEXP + e] > 0.f) atomicAdd(&s_cnt[e], 1);
  __syncthreads();
  if (tid == 0) {
    int acc = 0;
    for (int e = 0; e < NEXP; ++e) { s_off[e] = acc; acc += s_cnt[e]; }
  }
  __syncthreads();
  if (tid < NEXP) {
    s_cur[tid] = s_off[tid];
    meta[tid] = s_cnt[tid];
    meta[NEXP + tid] = s_off[tid];
  }
  __syncthreads();
  for (int t = tid; t < T_TOK; t += 256)
    for (int e = 0; e < NEXP; ++e)
      if (disp[t * NEXP + e] > 0.f) {
        int p = atomicAdd(&s_cur[e], 1);
        row_token[p] = t;
        row_comb[p] = comb[t * NEXP + e];
        int sl = atomicAdd(&s_tn[t], 1);
        tok2pair[t * 2 + sl] = p;
      }
  __syncthreads();
  if (tid == 0) {
    int nt = 0;
    for (int e = 0; e < NEXP; ++e)
      for (int m0 = 0; m0 < s_cnt[e]; m0 += 128)
        meta[17 + nt++] = (e << 16) | (m0 >> 7);
    meta[16] = nt;
  }
}

// ---------------- X -> bf16 once (3 MB) ----------------
__global__ void k_xbf(const float* __restrict__ X, unsigned short* __restrict__ Xb) {
  size_t i = ((size_t)blockIdx.x * 256 + threadIdx.x) * 8;
  float4 a = *(const float4*)(X + i);
  float4 b = *(const float4*)(X + i + 4);
  unsigned short r[8];
  r[0]=f2bf(a.x); r[1]=f2bf(a.y); r[2]=f2bf(a.z); r[3]=f2bf(a.w);
  r[4]=f2bf(b.x); r[5]=f2bf(b.y); r[6]=f2bf(b.z); r[7]=f2bf(b.w);
  *(uint4*)(Xb + i) = *(uint4*)r;
}

// ------- GEMM 1 fused: u = gelu(X@Wg^T) * (X@Wv^T) -> bf16 (P,H) -------
// Grid = 40 tile-slots x 24 n-tiles; tile table removes dead blocks.
__global__ __launch_bounds__(256, 2) void k_gemm_gv(
    const unsigned short* __restrict__ Xb,  // (T_TOK, DIM) bf16
    const float* __restrict__ Wg,           // (NEXP, HDIM, DIM)
    const float* __restrict__ Wv,
    const int* __restrict__ meta,
    const int* __restrict__ row_token,
    unsigned short* __restrict__ ubuf)      // (MAXP, HDIM) bf16
{
  int blk = blockIdx.x;
  int t = blk % NTILE_MAX;
  int nt = blk / NTILE_MAX;
  if (t >= meta[16]) return;
  int tv = meta[17 + t];
  int e = tv >> 16, m0 = (tv & 0xffff) << 7;
  int cnt = meta[e], off = meta[NEXP + e];
  int n0 = nt * 128;

  __shared__ unsigned short As[128 * LDST];
  __shared__ unsigned short Bgs[128 * LDST];
  __shared__ unsigned short Bvs[128 * LDST];

  int tid = threadIdx.x;
  int wid = tid >> 6, lane = tid & 63;
  int wm = (wid >> 1) * 64, wn = (wid & 1) * 64;
  int lr = lane & 15, quad = lane >> 4;

  // A gather rows: bf16, 128 rows x 4 16B-chunks = 512 chunks -> 2 rounds
  int a_tok[2];
#pragma unroll
  for (int r = 0; r < 2; ++r) {
    int row = (tid + 256 * r) >> 2;
    int gr = m0 + row; if (gr >= cnt) gr = cnt - 1;
    a_tok[r] = row_token[off + gr];
  }

  const float* Wgb = Wg + (size_t)e * ((size_t)HDIM * DIM);
  const float* Wvb = Wv + (size_t)e * ((size_t)HDIM * DIM);

  f32x4 zero4 = {0.f, 0.f, 0.f, 0.f};
  f32x4 accg[4][4], accv[4][4];
#pragma unroll
  for (int i = 0; i < 4; ++i)
#pragma unroll
    for (int j = 0; j < 4; ++j) { accg[i][j] = zero4; accv[i][j] = zero4; }

  for (int k0 = 0; k0 < DIM; k0 += 32) {
    __syncthreads();
#pragma unroll
    for (int r = 0; r < 2; ++r) {
      int c = tid + 256 * r;
      int row = c >> 2, sub = c & 3;
      uint4 av = *(const uint4*)(Xb + (size_t)a_tok[r] * DIM + k0 + sub * 8);
      *(uint4*)(&As[row * LDST + sub * 8]) = av;
    }
#pragma unroll
    for (int r = 0; r < 4; ++r) {
      int c = tid + 256 * r;
      int row = c >> 3, c4 = c & 7;
      float4 gv = *(const float4*)(Wgb + (size_t)(n0 + row) * DIM + k0 + c4 * 4);
      ushort4 gp;
      gp.x = f2bf(gv.x); gp.y = f2bf(gv.y); gp.z = f2bf(gv.z); gp.w = f2bf(gv.w);
      *(ushort4*)(&Bgs[row * LDST + c4 * 4]) = gp;
      float4 vv = *(const float4*)(Wvb + (size_t)(n0 + row) * DIM + k0 + c4 * 4);
      ushort4 vp;
      vp.x = f2bf(vv.x); vp.y = f2bf(vv.y); vp.z = f2bf(vv.z); vp.w = f2bf(vv.w);
      *(ushort4*)(&Bvs[row * LDST + c4 * 4]) = vp;
    }
    __syncthreads();
    bfrag a[4], bg[4], bv[4];
#pragma unroll
    for (int i = 0; i < 4; ++i)
      a[i] = *(const bfrag*)(&As[(wm + i * 16 + lr) * LDST + quad * 8]);
#pragma unroll
    for (int j = 0; j < 4; ++j) {
      bg[j] = *(const bfrag*)(&Bgs[(wn + j * 16 + lr) * LDST + quad * 8]);
      bv[j] = *(const bfrag*)(&Bvs[(wn + j * 16 + lr) * LDST + quad * 8]);
    }
#pragma unroll
    for (int i = 0; i < 4; ++i)
#pragma unroll
      for (int j = 0; j < 4; ++j) {
        accg[i][j] = __builtin_amdgcn_mfma_f32_16x16x32_bf16(a[i], bg[j], accg[i][j], 0, 0, 0);
        accv[i][j] = __builtin_amdgcn_mfma_f32_16x16x32_bf16(a[i], bv[j], accv[i][j], 0, 0, 0);
      }
  }

  // epilogue: gelu_exact(g)*v on fp32 accumulators
#pragma unroll
  for (int i = 0; i < 4; ++i)
#pragma unroll
    for (int rg = 0; rg < 4; ++rg) {
      int gr = m0 + wm + i * 16 + quad * 4 + rg;
      if (gr < cnt) {
        size_t base = (size_t)(off + gr) * HDIM + n0 + wn;
#pragma unroll
        for (int j = 0; j < 4; ++j) {
          float g = accg[i][j][rg];
          float v = accv[i][j][rg];
          float u = 0.5f * g * (1.0f + erff(g * 0.70710678118654752f)) * v;
          ubuf[base + j * 16 + lr] = f2bf(u);
        }
      }
    }
}

// ------- GEMM 2: u @ Wo^T, split-K x4. mode 0: store w-scaled partials;
//         mode 1: atomicAdd into pre-zeroed out (small-ws fallback). -------
__global__ __launch_bounds__(256, 2) void k_gemm_out(
    const unsigned short* __restrict__ U,  // (MAXP, HDIM) bf16
    const float* __restrict__ Wo,          // (NEXP, DIM, HDIM)
    const float* __restrict__ scale,
    const int* __restrict__ meta,
    const int* __restrict__ row_token,
    const float* __restrict__ row_comb,
    float* __restrict__ partial,           // (4, MAXP, DIM)
    float* __restrict__ out,               // (T_TOK, DIM)
    int mode)
{
  int blk = blockIdx.x;                    // 40 * 6 * 4 = 960
  int t = blk % NTILE_MAX;
  int rest = blk / NTILE_MAX;
  int nt = rest % 6;
  int ks = rest / 6;
  if (t >= meta[16]) return;
  int tv = meta[17 + t];
  int e = tv >> 16, m0 = (tv & 0xffff) << 7;
  int cnt = meta[e], off = meta[NEXP + e];
  int n0 = nt * 128;
  int kbase = ks * (HDIM / 4);

  __shared__ unsigned short As[128 * LDST];
  __shared__ unsigned short Bs[128 * LDST];

  int tid = threadIdx.x;
  int wid = tid >> 6, lane = tid & 63;
  int wm = (wid >> 1) * 64, wn = (wid & 1) * 64;
  int lr = lane & 15, quad = lane >> 4;

  int a_grow[2];
#pragma unroll
  for (int r = 0; r < 2; ++r) {
    int row = (tid + 256 * r) >> 2;
    int gr = m0 + row; if (gr >= cnt) gr = cnt - 1;
    a_grow[r] = off + gr;
  }

  const float* Wb = Wo + (size_t)e * ((size_t)DIM * HDIM);

  f32x4 zero4 = {0.f, 0.f, 0.f, 0.f};
  f32x4 acc[4][4];
#pragma unroll
  for (int i = 0; i < 4; ++i)
#pragma unroll
    for (int j = 0; j < 4; ++j) acc[i][j] = zero4;

  for (int kk = 0; kk < HDIM / 4; kk += 32) {
    int k0 = kbase + kk;
    __syncthreads();
#pragma unroll
    for (int r = 0; r < 2; ++r) {
      int c = tid + 256 * r;
      int row = c >> 2, sub = c & 3;
      uint4 av = *(const uint4*)(U + (size_t)a_grow[r] * HDIM + k0 + sub * 8);
      *(uint4*)(&As[row * LDST + sub * 8]) = av;
    }
#pragma unroll
    for (int r = 0; r < 4; ++r) {
      int c = tid + 256 * r;
      int row = c >> 3, c4 = c & 7;
      float4 bvv = *(const float4*)(Wb + (size_t)(n0 + row) * HDIM + k0 + c4 * 4);
      ushort4 bp;
      bp.x = f2bf(bvv.x); bp.y = f2bf(bvv.y); bp.z = f2bf(bvv.z); bp.w = f2bf(bvv.w);
      *(ushort4*)(&Bs[row * LDST + c4 * 4]) = bp;
    }
    __syncthreads();
    bfrag a[4], b[4];
#pragma unroll
    for (int i = 0; i < 4; ++i)
      a[i] = *(const bfrag*)(&As[(wm + i * 16 + lr) * LDST + quad * 8]);
#pragma unroll
    for (int j = 0; j < 4; ++j)
      b[j] = *(const bfrag*)(&Bs[(wn + j * 16 + lr) * LDST + quad * 8]);
#pragma unroll
    for (int i = 0; i < 4; ++i)
#pragma unroll
      for (int j = 0; j < 4; ++j)
        acc[i][j] = __builtin_amdgcn_mfma_f32_16x16x32_bf16(a[i], b[j], acc[i][j], 0, 0, 0);
  }

  float sc = scale[e];
#pragma unroll
  for (int i = 0; i < 4; ++i)
#pragma unroll
    for (int rg = 0; rg < 4; ++rg) {
      int gr = m0 + wm + i * 16 + quad * 4 + rg;
      if (gr < cnt) {
        int grow = off + gr;
        float w = row_comb[grow] * sc;
        if (mode == 0) {
          float* pb = partial + ((size_t)ks * MAXP + grow) * DIM + n0 + wn;
#pragma unroll
          for (int j = 0; j < 4; ++j)
            pb[j * 16 + lr] = acc[i][j][rg] * w;
        } else {
          int tok = row_token[grow];
          float* ob = out + (size_t)tok * DIM + n0 + wn;
#pragma unroll
          for (int j = 0; j < 4; ++j)
            atomicAdd(ob + j * 16 + lr, acc[i][j][rg] * w);
        }
      }
    }
}

// ---------------- combine: out[t] = sum over 2 pairs x 4 K-splits ----------------
__global__ void k_combine(const float* __restrict__ partial,
                          const int* __restrict__ tok2pair,
                          float* __restrict__ out) {
  int idx = blockIdx.x * 256 + threadIdx.x;   // 2048 * 192 = 393216
  int t = idx / 192, d4 = idx % 192;
  int p0 = tok2pair[t * 2], p1 = tok2pair[t * 2 + 1];
  float sx = 0.f, sy = 0.f, sz = 0.f, sw = 0.f;
#pragma unroll
  for (int ks = 0; ks < 4; ++ks) {
    float4 a = *(const float4*)(partial + ((size_t)ks * MAXP + p0) * DIM + d4 * 4);
    float4 b = *(const float4*)(partial + ((size_t)ks * MAXP + p1) * DIM + d4 * 4);
    sx += a.x + b.x; sy += a.y + b.y; sz += a.z + b.z; sw += a.w + b.w;
  }
  float4 r; r.x = sx; r.y = sy; r.z = sz; r.w = sw;
  *(float4*)(out + (size_t)t * DIM + d4 * 4) = r;
}

extern "C" void kernel_launch(void* const* d_in, const int* in_sizes, int n_in,
                              void* d_out, int out_size, void* d_ws, size_t ws_size,
                              hipStream_t stream) {
  const float* tokens = (const float*)d_in[0];
  const float* disp   = (const float*)d_in[1];
  const float* comb   = (const float*)d_in[2];
  const float* Wg     = (const float*)d_in[3];
  const float* Wv     = (const float*)d_in[4];
  const float* Wo     = (const float*)d_in[5];
  const float* scale  = (const float*)d_in[6];
  float* out = (float*)d_out;

  char* ws = (char*)d_ws;
  int*   meta      = (int*)ws;                        // 57 ints
  int*   row_token = (int*)(ws + 16384);
  float* row_comb  = (float*)(ws + 32768);
  int*   tok2pair  = (int*)(ws + 49152);
  unsigned short* Xb   = (unsigned short*)(ws + (1u << 20));            // 3 MB
  unsigned short* ubuf = (unsigned short*)(ws + (5u << 20));            // 24 MB
  float* partial = (float*)(ws + (32ull << 20));                        // 48 MB
  size_t need_partial = (32ull << 20) + (size_t)4 * MAXP * DIM * sizeof(float);
  int mode = (ws_size >= need_partial) ? 0 : 1;

  hipLaunchKernelGGL(k_route, dim3(1), dim3(256), 0, stream,
                     disp, comb, meta, row_comb, row_token, tok2pair);
  hipLaunchKernelGGL(k_xbf, dim3((T_TOK * DIM) / (256 * 8)), dim3(256), 0, stream,
                     tokens, Xb);
  hipLaunchKernelGGL(k_gemm_gv, dim3(NTILE_MAX * 24), dim3(256), 0, stream,
                     Xb, Wg, Wv, meta, row_token, ubuf);
  if (mode == 1)
    hipMemsetAsync(d_out, 0, (size_t)out_size * sizeof(float), stream);
  hipLaunchKernelGGL(k_gemm_out, dim3(NTILE_MAX * 6 * 4), dim3(256), 0, stream,
                     ubuf, Wo, scale, meta, row_token, row_comb, partial, out, mode);
  if (mode == 0)
    hipLaunchKernelGGL(k_combine, dim3((T_TOK * DIM / 4) / 256), dim3(256), 0, stream,
                       partial, tok2pair, out);
}